// Round 17
// baseline (175.163 us; speedup 1.0000x reference)
//
#include <hip/hip_runtime.h>
#include <math.h>

#define B_ 2
#define S_ 2048
#define E_ 1024
#define H_ 16
#define DH_ 64
#define NE3_ 3072
#define MTOT_ (B_*S_)
#define QSCALE_ 0.18033688011112042f   // 0.125 * log2(e); P = exp2(s')

typedef __bf16 bf16;
typedef bf16 bf16x8 __attribute__((ext_vector_type(8)));
typedef bf16 bf16x4 __attribute__((ext_vector_type(4)));
typedef float f32x4 __attribute__((ext_vector_type(4)));
typedef float f32x16 __attribute__((ext_vector_type(16)));
typedef unsigned u32x2 __attribute__((ext_vector_type(2)));
typedef unsigned u32x4 __attribute__((ext_vector_type(4)));

#define MFMA16(a,b,c) __builtin_amdgcn_mfma_f32_16x16x32_bf16(a,b,c,0,0,0)
#define MFMA32(a,b,c) __builtin_amdgcn_mfma_f32_32x32x16_bf16(a,b,c,0,0,0)

// XOR swizzle for row-major staging (GEMM inputs only)
#define F_(r) ((((r) & 7) ^ (((r) >> 3) & 7)))

__device__ inline void* lds_swz(void* base, int row, int bytecol) {
    return (char*)base + row * 128 + (bytecol ^ (F_(row) << 4));
}

__device__ inline unsigned cvt_pk_bf16(float lo, float hi) {
    unsigned r;
    asm("v_cvt_pk_bf16_f32 %0, %1, %2" : "=v"(r) : "v"(lo), "v"(hi));
    return r;
}

// v_permlane32_swap x, y: after: x = [x.lo | y.lo], y = [x.hi | y.hi]
__device__ inline void permswap32(unsigned &x, unsigned &y) {
    u32x2 r = __builtin_amdgcn_permlane32_swap(x, y, false, false);
    x = r.x; y = r.y;
}

__device__ inline float exp2_hw(float x) {
    float r;
    asm("v_exp_f32 %0, %1" : "=v"(r) : "v"(x));
    return r;
}

__device__ inline void gload_lds16(const void* g, void* l) {
    __builtin_amdgcn_global_load_lds(
        (const __attribute__((address_space(1))) void*)g,
        (__attribute__((address_space(3))) void*)l, 16, 0, 0);
}

// ---------------- fp32 -> bf16 convert, all three arrays in one launch --------
#define NX_ (MTOT_*E_)
#define NW_ (NE3_*E_)
#define NWO_ (E_*E_)
__global__ void k_f2b3(const float* __restrict__ x, const float* __restrict__ wq,
                       const float* __restrict__ wo,
                       bf16* __restrict__ xb, bf16* __restrict__ wqb,
                       bf16* __restrict__ wob) {
    const int i = blockIdx.x * 256 + threadIdx.x;
    const int idx = i * 4;
    const float* src; bf16* dst; int off;
    if (idx < NX_)            { src = x;  dst = xb;  off = idx; }
    else if (idx < NX_ + NW_) { src = wq; dst = wqb; off = idx - NX_; }
    else                      { src = wo; dst = wob; off = idx - NX_ - NW_; }
    float4 f = *reinterpret_cast<const float4*>(src + off);
    bf16x4 o;
    o[0] = (bf16)f.x; o[1] = (bf16)f.y; o[2] = (bf16)f.z; o[3] = (bf16)f.w;
    *reinterpret_cast<bf16x4*>(dst + off) = o;
}

// ---------------- GEMM: C = A @ W^T (+bias), 512 threads / 8 waves ----------------
template<int MODE>
__global__ __launch_bounds__(512) void k_gemm(
    const bf16* __restrict__ A, const bf16* __restrict__ W,
    const float* __restrict__ bias,
    bf16* __restrict__ Qf, bf16* __restrict__ Kf, bf16* __restrict__ Vf,
    float* __restrict__ out)
{
    constexpr int NBUF = (MODE == 0) ? 1 : 2;
    __shared__ __align__(16) bf16 At[NBUF][128*64];
    __shared__ __align__(16) bf16 Bt[NBUF][128*64];
    const int tid = threadIdx.x, lane = tid & 63, w = tid >> 6;
    const int lq = lane & 15, lh = lane >> 4;
    const int wr = w >> 2, wc = w & 3;
    const int g = blockIdx.x;
    const int nxw = (MODE == 0 ? 3 : 1);
    const int xcd = g & 7, li = g >> 3;
    const int m0 = (li & 31) * 128;
    const int n0 = (xcd * nxw + (li >> 5)) * 128;

    f32x4 acc[2][4] = {};

    auto stage = [&](int k0, int buf) {
        #pragma unroll
        for (int j = 0; j < 2; ++j) {
            const int idx = j*512 + tid;
            const int row = idx >> 3;
            const int colx = ((idx & 7) * 8) ^ (F_(row) * 8);
            gload_lds16(A + (size_t)(m0 + row) * E_ + k0 + colx, &At[buf][idx * 8]);
            gload_lds16(W + (size_t)(n0 + row) * E_ + k0 + colx, &Bt[buf][idx * 8]);
        }
    };
    auto compute = [&](int buf) {
        #pragma unroll
        for (int ks = 0; ks < 2; ++ks) {
            const int bc = ks * 64 + 16 * lh;
            bf16x8 a[4], b[2];
            #pragma unroll
            for (int j = 0; j < 4; ++j)
                a[j] = *(const bf16x8*)lds_swz(&At[buf][0], wr*64 + j*16 + lq, bc);
            #pragma unroll
            for (int i = 0; i < 2; ++i)
                b[i] = *(const bf16x8*)lds_swz(&Bt[buf][0], wc*32 + i*16 + lq, bc);
            #pragma unroll
            for (int i = 0; i < 2; ++i)
                #pragma unroll
                for (int j = 0; j < 4; ++j)
                    acc[i][j] = MFMA16(b[i], a[j], acc[i][j]);
        }
    };

    if constexpr (MODE == 0) {
        stage(0, 0);
        __syncthreads();
        for (int kt = 0; kt < E_/64; ++kt) {
            compute(0);
            if (kt + 1 < E_/64) {
                __syncthreads();
                stage((kt + 1) * 64, 0);
                __syncthreads();
            }
        }
    } else {
        stage(0, 0);
        __syncthreads();
        int cur = 0;
        for (int kt = 0; kt < E_/64; ++kt) {
            if (kt + 1 < E_/64) stage((kt + 1) * 64, cur ^ 1);
            compute(cur);
            cur ^= 1;
            if (kt + 1 < E_/64) __syncthreads();
        }
    }

    const int mW = m0 + wr*64;
    #pragma unroll
    for (int i = 0; i < 2; ++i) {
        const int n4 = n0 + wc*32 + i*16 + lh * 4;
        const float4 b4 = *reinterpret_cast<const float4*>(&bias[n4]);
        const float* bp = reinterpret_cast<const float*>(&b4);
        if constexpr (MODE == 0) {
            const int t = n4 >> 10, h = (n4 >> 6) & 15, d0 = n4 & 63;
            #pragma unroll
            for (int j = 0; j < 4; ++j) {
                const int m = mW + j*16 + lq;
                const int bb_i = m >> 11, s = m & 2047;
                const size_t bhb = ((size_t)(bb_i*H_ + h)) * 131072;
                if (t == 2) {
                    for (int r = 0; r < 4; ++r) {
                        const int d = d0 + r;
                        const size_t e = bhb + (size_t)(s >> 6) * 4096
                                       + ((d >> 5) * 4 + ((s >> 4) & 3)) * 512
                                       + ((d & 31) + 32 * ((s >> 3) & 1)) * 8
                                       + (s & 7);
                        Vf[e] = (bf16)(acc[i][j][r] + bp[r]);
                    }
                } else {
                    bf16* dst = (t == 0) ? Qf : Kf;
                    const float sc = (t == 0) ? QSCALE_ : 1.0f;
                    const size_t e = bhb + (size_t)(s >> 6) * 4096
                                   + (((s >> 5) & 1) * 4 + (d0 >> 4)) * 512
                                   + ((s & 31) + 32 * ((d0 >> 3) & 1)) * 8
                                   + (d0 & 7);
                    bf16x4 o;
                    for (int r = 0; r < 4; ++r)
                        o[r] = (bf16)((acc[i][j][r] + bp[r]) * sc);
                    *reinterpret_cast<bf16x4*>(dst + e) = o;
                }
            }
        } else {
            #pragma unroll
            for (int j = 0; j < 4; ++j) {
                const int m = mW + j*16 + lq;
                float4 o;
                o.x = acc[i][j][0] + bp[0];
                o.y = acc[i][j][1] + bp[1];
                o.z = acc[i][j][2] + bp[2];
                o.w = acc[i][j][3] + bp[3];
                *reinterpret_cast<float4*>(out + (size_t)m * E_ + n4) = o;
            }
        }
    }
}

// ---------------- pass 1: l_k = sum_q exp2(S'[q,k]); fold 1/l into Vf -----------
// k-block 64, 2 waves (128 thr), grid 1024 -> 4 blocks/CU.
__global__ __launch_bounds__(128) void k_colsum(
    const bf16* __restrict__ Qf, const bf16* __restrict__ Kf,
    bf16* __restrict__ Vf)
{
    __shared__ __align__(16) char smem[40960];
    __shared__ float rlbuf[64];
    char* Kl   = smem;            // 8KB (64 k = 1 tile)
    char* Qbuf = smem + 8192;     // 2 x 16KB
    const int tid = threadIdx.x, lane = tid & 63, w = tid >> 6;
    const int l16 = lane * 16;
    const int g = blockIdx.x, xcd = g & 7, li = g >> 3;
    const int bh = xcd * 4 + (li >> 5);
    const int k0 = (li & 31) * 64;
    const bf16* Kbase = Kf + (size_t)bh * 131072 + (size_t)(k0 >> 6) * 4096;
    const bf16* Qbase = Qf + (size_t)bh * 131072;

    #pragma unroll
    for (int j = 0; j < 4; ++j)
        gload_lds16(Kbase + (j*128 + tid)*8, Kl + (j*128 + w*64)*16);
    auto stageQ = [&](int qt, int buf) {
        const bf16* qb = Qbase + (size_t)qt * 8192;
        #pragma unroll
        for (int j = 0; j < 8; ++j)
            gload_lds16(qb + (j*128 + tid)*8, Qbuf + buf*16384 + (j*128 + w*64)*16);
    };
    stageQ(0, 0);
    __syncthreads();

    bf16x8 bk[4];   // wave's 32 k-rows, 4 dh-slices
    #pragma unroll
    for (int sl = 0; sl < 4; ++sl)
        bk[sl] = *(const bf16x8*)(Kl + w*4096 + sl*1024 + l16);

    float lsum = 0.f;
    int cur = 0;
    for (int qt = 0; qt < S_/128; ++qt) {
        if (qt + 1 < S_/128) stageQ(qt + 1, cur ^ 1);
        #pragma unroll
        for (int qs = 0; qs < 4; ++qs) {
            f32x16 s = {};
            __builtin_amdgcn_s_setprio(1);
            #pragma unroll
            for (int sl = 0; sl < 4; ++sl) {
                bf16x8 aq = *(const bf16x8*)(Qbuf + cur*16384 + (qs*4+sl)*1024 + l16);
                s = MFMA32(aq, bk[sl], s);
            }
            __builtin_amdgcn_s_setprio(0);
            #pragma unroll
            for (int r = 0; r < 16; ++r)
                lsum += exp2_hw(s[r]);
        }
        cur ^= 1;
        if (qt + 1 < S_/128) __syncthreads();
    }
    lsum += __shfl_xor(lsum, 32);
    if (lane < 32)
        rlbuf[w*32 + lane] = 1.0f / lsum;
    __syncthreads();

    // scale Vf for k in [k0, k0+64): 1 tile = 4096 elems = 512 vec8
    bf16* Vb = Vf + (size_t)bh * 131072 + (size_t)(k0 >> 6) * 4096;
    for (int c = 0; c < 4; ++c) {
        const int v = c*128 + tid;               // 0..511
        const int kb = ((v >> 6) & 3)*16 + ((v >> 5) & 1)*8;
        bf16x8* p = reinterpret_cast<bf16x8*>(Vb + v*8);
        bf16x8 x = *p, o;
        #pragma unroll
        for (int jj = 0; jj < 8; ++jj)
            o[jj] = (bf16)((float)x[jj] * rlbuf[kb + jj]);
        *p = o;
    }
}

// ---------------- pass 2: O = exp2(S') @ V'; q-block 64, 2 waves, grid 1024 ----
__global__ __launch_bounds__(128) void k_attn(
    const bf16* __restrict__ Qf, const bf16* __restrict__ Kf,
    const bf16* __restrict__ Vf, bf16* __restrict__ AO)
{
    __shared__ __align__(16) char smem[40960];
    char* QP   = smem;            // 8KB Q stage (dead after hoist)
    char* Kbuf = smem + 8192;     // 2 x 8KB
    char* Vbuf = smem + 24576;    // 2 x 8KB
    const int tid = threadIdx.x, lane = tid & 63, w = tid >> 6;
    const int l16 = lane * 16;
    const int g = blockIdx.x, xcd = g & 7, li = g >> 3;
    const int bh = xcd * 4 + (li >> 5);
    const int q0 = (li & 31) * 64;
    const bf16* Qbase = Qf + (size_t)bh * 131072 + (size_t)(q0 >> 6) * 4096;
    const bf16* Kbase = Kf + (size_t)bh * 131072;
    const bf16* Vbase = Vf + (size_t)bh * 131072;

    #pragma unroll
    for (int j = 0; j < 4; ++j)
        gload_lds16(Qbase + (j*128 + tid)*8, QP + (j*128 + w*64)*16);
    auto stageKV = [&](int kt, int buf) {
        const bf16* kb = Kbase + (size_t)kt * 4096;
        const bf16* vb = Vbase + (size_t)kt * 4096;
        #pragma unroll
        for (int j = 0; j < 4; ++j) {
            gload_lds16(kb + (j*128 + tid)*8, Kbuf + buf*8192 + (j*128 + w*64)*16);
            gload_lds16(vb + (j*128 + tid)*8, Vbuf + buf*8192 + (j*128 + w*64)*16);
        }
    };
    stageKV(0, 0);
    __syncthreads();

    // hoist Q B-frags: wave's 32 q rows, 4 dh-slices (16 VGPR)
    bf16x8 bq[4];
    #pragma unroll
    for (int sl = 0; sl < 4; ++sl)
        bq[sl] = *(const bf16x8*)(QP + w*4096 + sl*1024 + l16);

    f32x16 oacc[2] = {};
    int cur = 0;
    for (int t = 0; t < S_/64; ++t) {
        if (t + 1 < S_/64) stageKV(t + 1, cur ^ 1);
        char* Kc = Kbuf + cur*8192;
        char* Vc = Vbuf + cur*8192;

        #pragma unroll
        for (int kt = 0; kt < 2; ++kt) {
            // QK^T (swapped): D[k][q], k-tile kt
            f32x16 s = {};
            __builtin_amdgcn_s_setprio(1);
            #pragma unroll
            for (int sl = 0; sl < 4; ++sl) {
                bf16x8 ak = *(const bf16x8*)(Kc + (kt*4+sl)*1024 + l16);
                s = MFMA32(ak, bq[sl], s);
            }
            __builtin_amdgcn_s_setprio(0);

            // P = exp2 -> pack -> in-register B-frags via permlane32_swap.
            unsigned a[8];
            #pragma unroll
            for (int gg = 0; gg < 8; ++gg)
                a[gg] = cvt_pk_bf16(exp2_hw(s[2*gg]), exp2_hw(s[2*gg+1]));

            #pragma unroll
            for (int kl = 0; kl < 2; ++kl) {
                unsigned m0 = a[4*kl + 0], m2 = a[4*kl + 2];
                unsigned m1 = a[4*kl + 1], m3 = a[4*kl + 3];
                permswap32(m0, m2);
                permswap32(m1, m3);
                u32x4 pw = {m0, m1, m2, m3};
                bf16x8 pf = __builtin_bit_cast(bf16x8, pw);
                const int ksl = kt*2 + kl;
                __builtin_amdgcn_s_setprio(1);
                #pragma unroll
                for (int dt = 0; dt < 2; ++dt) {
                    bf16x8 av = *(const bf16x8*)(Vc + (dt*4+ksl)*1024 + l16);
                    oacc[dt] = MFMA32(av, pf, oacc[dt]);
                }
                __builtin_amdgcn_s_setprio(0);
            }
        }
        cur ^= 1;
        if (t + 1 < S_/64) __syncthreads();
    }

    // epilogue: O^T[d][q]: col q = lane&31, row d = dt*32 + r + 8*rg + 4*(lane>>5)
    const int b = bh >> 4, h = bh & 15;
    const int q = q0 + w*32 + (lane & 31);
    const int hi4 = (lane >> 5) * 4;
    bf16* aob = AO + ((size_t)(b*S_ + q))*E_ + h*DH_;
    #pragma unroll
    for (int dt = 0; dt < 2; ++dt)
        #pragma unroll
        for (int rg = 0; rg < 4; ++rg) {
            const int dbase = dt*32 + 8*rg + hi4;
            bf16x4 o;
            #pragma unroll
            for (int r = 0; r < 4; ++r) o[r] = (bf16)oacc[dt][rg*4 + r];
            *reinterpret_cast<bf16x4*>(aob + dbase) = o;
        }
}

extern "C" void kernel_launch(void* const* d_in, const int* in_sizes, int n_in,
                              void* d_out, int out_size, void* d_ws, size_t ws_size,
                              hipStream_t stream) {
    const float* input = (const float*)d_in[0];
    const float* Wqkv  = (const float*)d_in[1];
    const float* bqkv  = (const float*)d_in[2];
    const float* Wo    = (const float*)d_in[3];
    const float* bo    = (const float*)d_in[4];
    float* out = (float*)d_out;

    char* ws = (char*)d_ws;
    bf16*  Xb   = (bf16*) (ws + 0);
    bf16*  Wqb  = (bf16*) (ws + 8388608);
    bf16*  Wob  = (bf16*) (ws + 14680064);
    bf16*  Qfg  = (bf16*) (ws + 16777216);
    bf16*  Kfg  = (bf16*) (ws + 25165824);
    bf16*  Vfg  = (bf16*) (ws + 33554432);
    bf16*  AO   = (bf16*) (ws + 41943040);

    k_f2b3<<<(NX_ + NW_ + NWO_) / 1024, 256, 0, stream>>>(
        input, Wqkv, Wo, Xb, Wqb, Wob);

    k_gemm<0><<<768, 512, 0, stream>>>(Xb, Wqb, bqkv, Qfg, Kfg, Vfg, nullptr);

    k_colsum<<<1024, 128, 0, stream>>>(Qfg, Kfg, Vfg);

    k_attn<<<1024, 128, 0, stream>>>(Qfg, Kfg, Vfg, AO);

    k_gemm<1><<<256, 512, 0, stream>>>(AO, Wob, bo, nullptr, nullptr, nullptr, out);
}

// Round 18
// 145.804 us; speedup vs baseline: 1.2014x; 1.2014x over previous
//
#include <hip/hip_runtime.h>
#include <math.h>

#define B_ 2
#define S_ 2048
#define E_ 1024
#define H_ 16
#define DH_ 64
#define NE3_ 3072
#define MTOT_ (B_*S_)
#define QSCALE_ 0.18033688011112042f   // 0.125 * log2(e); P = exp2(s')

typedef __bf16 bf16;
typedef bf16 bf16x8 __attribute__((ext_vector_type(8)));
typedef bf16 bf16x4 __attribute__((ext_vector_type(4)));
typedef float f32x4 __attribute__((ext_vector_type(4)));
typedef float f32x16 __attribute__((ext_vector_type(16)));
typedef unsigned u32x2 __attribute__((ext_vector_type(2)));
typedef unsigned u32x4 __attribute__((ext_vector_type(4)));

#define MFMA16(a,b,c) __builtin_amdgcn_mfma_f32_16x16x32_bf16(a,b,c,0,0,0)
#define MFMA32(a,b,c) __builtin_amdgcn_mfma_f32_32x32x16_bf16(a,b,c,0,0,0)

// XOR swizzle for row-major staging (GEMM inputs only)
#define F_(r) ((((r) & 7) ^ (((r) >> 3) & 7)))

__device__ inline void* lds_swz(void* base, int row, int bytecol) {
    return (char*)base + row * 128 + (bytecol ^ (F_(row) << 4));
}

__device__ inline unsigned cvt_pk_bf16(float lo, float hi) {
    unsigned r;
    asm("v_cvt_pk_bf16_f32 %0, %1, %2" : "=v"(r) : "v"(lo), "v"(hi));
    return r;
}

// v_permlane32_swap x, y: after: x = [x.lo | y.lo], y = [x.hi | y.hi]
__device__ inline void permswap32(unsigned &x, unsigned &y) {
    u32x2 r = __builtin_amdgcn_permlane32_swap(x, y, false, false);
    x = r.x; y = r.y;
}

__device__ inline float exp2_hw(float x) {
    float r;
    asm("v_exp_f32 %0, %1" : "=v"(r) : "v"(x));
    return r;
}

__device__ inline void gload_lds16(const void* g, void* l) {
    __builtin_amdgcn_global_load_lds(
        (const __attribute__((address_space(1))) void*)g,
        (__attribute__((address_space(3))) void*)l, 16, 0, 0);
}

// ---------------- fp32 -> bf16 convert, all three arrays in one launch --------
#define NX_ (MTOT_*E_)
#define NW_ (NE3_*E_)
#define NWO_ (E_*E_)
__global__ void k_f2b3(const float* __restrict__ x, const float* __restrict__ wq,
                       const float* __restrict__ wo,
                       bf16* __restrict__ xb, bf16* __restrict__ wqb,
                       bf16* __restrict__ wob) {
    const int i = blockIdx.x * 256 + threadIdx.x;
    const int idx = i * 4;
    const float* src; bf16* dst; int off;
    if (idx < NX_)            { src = x;  dst = xb;  off = idx; }
    else if (idx < NX_ + NW_) { src = wq; dst = wqb; off = idx - NX_; }
    else                      { src = wo; dst = wob; off = idx - NX_ - NW_; }
    float4 f = *reinterpret_cast<const float4*>(src + off);
    bf16x4 o;
    o[0] = (bf16)f.x; o[1] = (bf16)f.y; o[2] = (bf16)f.z; o[3] = (bf16)f.w;
    *reinterpret_cast<bf16x4*>(dst + off) = o;
}

// ---------------- GEMM: C = A @ W^T (+bias), 512 threads / 8 waves ----------------
template<int MODE>
__global__ __launch_bounds__(512) void k_gemm(
    const bf16* __restrict__ A, const bf16* __restrict__ W,
    const float* __restrict__ bias,
    bf16* __restrict__ Qf, bf16* __restrict__ Kf, bf16* __restrict__ Vf,
    float* __restrict__ out)
{
    constexpr int NBUF = (MODE == 0) ? 1 : 2;
    __shared__ __align__(16) bf16 At[NBUF][128*64];
    __shared__ __align__(16) bf16 Bt[NBUF][128*64];
    const int tid = threadIdx.x, lane = tid & 63, w = tid >> 6;
    const int lq = lane & 15, lh = lane >> 4;
    const int wr = w >> 2, wc = w & 3;
    const int g = blockIdx.x;
    const int nxw = (MODE == 0 ? 3 : 1);
    const int xcd = g & 7, li = g >> 3;
    const int m0 = (li & 31) * 128;
    const int n0 = (xcd * nxw + (li >> 5)) * 128;

    f32x4 acc[2][4] = {};

    auto stage = [&](int k0, int buf) {
        #pragma unroll
        for (int j = 0; j < 2; ++j) {
            const int idx = j*512 + tid;
            const int row = idx >> 3;
            const int colx = ((idx & 7) * 8) ^ (F_(row) * 8);
            gload_lds16(A + (size_t)(m0 + row) * E_ + k0 + colx, &At[buf][idx * 8]);
            gload_lds16(W + (size_t)(n0 + row) * E_ + k0 + colx, &Bt[buf][idx * 8]);
        }
    };
    auto compute = [&](int buf) {
        #pragma unroll
        for (int ks = 0; ks < 2; ++ks) {
            const int bc = ks * 64 + 16 * lh;
            bf16x8 a[4], b[2];
            #pragma unroll
            for (int j = 0; j < 4; ++j)
                a[j] = *(const bf16x8*)lds_swz(&At[buf][0], wr*64 + j*16 + lq, bc);
            #pragma unroll
            for (int i = 0; i < 2; ++i)
                b[i] = *(const bf16x8*)lds_swz(&Bt[buf][0], wc*32 + i*16 + lq, bc);
            #pragma unroll
            for (int i = 0; i < 2; ++i)
                #pragma unroll
                for (int j = 0; j < 4; ++j)
                    acc[i][j] = MFMA16(b[i], a[j], acc[i][j]);
        }
    };

    if constexpr (MODE == 0) {
        stage(0, 0);
        __syncthreads();
        for (int kt = 0; kt < E_/64; ++kt) {
            compute(0);
            if (kt + 1 < E_/64) {
                __syncthreads();
                stage((kt + 1) * 64, 0);
                __syncthreads();
            }
        }
    } else {
        stage(0, 0);
        __syncthreads();
        int cur = 0;
        for (int kt = 0; kt < E_/64; ++kt) {
            if (kt + 1 < E_/64) stage((kt + 1) * 64, cur ^ 1);
            compute(cur);
            cur ^= 1;
            if (kt + 1 < E_/64) __syncthreads();
        }
    }

    const int mW = m0 + wr*64;
    #pragma unroll
    for (int i = 0; i < 2; ++i) {
        const int n4 = n0 + wc*32 + i*16 + lh * 4;
        const float4 b4 = *reinterpret_cast<const float4*>(&bias[n4]);
        const float* bp = reinterpret_cast<const float*>(&b4);
        if constexpr (MODE == 0) {
            const int t = n4 >> 10, h = (n4 >> 6) & 15, d0 = n4 & 63;
            #pragma unroll
            for (int j = 0; j < 4; ++j) {
                const int m = mW + j*16 + lq;
                const int bb_i = m >> 11, s = m & 2047;
                const size_t bhb = ((size_t)(bb_i*H_ + h)) * 131072;
                if (t == 2) {
                    for (int r = 0; r < 4; ++r) {
                        const int d = d0 + r;
                        const size_t e = bhb + (size_t)(s >> 6) * 4096
                                       + ((d >> 5) * 4 + ((s >> 4) & 3)) * 512
                                       + ((d & 31) + 32 * ((s >> 3) & 1)) * 8
                                       + (s & 7);
                        Vf[e] = (bf16)(acc[i][j][r] + bp[r]);
                    }
                } else {
                    bf16* dst = (t == 0) ? Qf : Kf;
                    const float sc = (t == 0) ? QSCALE_ : 1.0f;
                    const size_t e = bhb + (size_t)(s >> 6) * 4096
                                   + (((s >> 5) & 1) * 4 + (d0 >> 4)) * 512
                                   + ((s & 31) + 32 * ((d0 >> 3) & 1)) * 8
                                   + (d0 & 7);
                    bf16x4 o;
                    for (int r = 0; r < 4; ++r)
                        o[r] = (bf16)((acc[i][j][r] + bp[r]) * sc);
                    *reinterpret_cast<bf16x4*>(dst + e) = o;
                }
            }
        } else {
            #pragma unroll
            for (int j = 0; j < 4; ++j) {
                const int m = mW + j*16 + lq;
                float4 o;
                o.x = acc[i][j][0] + bp[0];
                o.y = acc[i][j][1] + bp[1];
                o.z = acc[i][j][2] + bp[2];
                o.w = acc[i][j][3] + bp[3];
                *reinterpret_cast<float4*>(out + (size_t)m * E_ + n4) = o;
            }
        }
    }
}

// ---------------- pass 1: l_k = sum_q exp2(S'[q,k]); fold 1/l into Vf -----------
// (r15-verified version: 256 threads, k-block 128)
__global__ __launch_bounds__(256) void k_colsum(
    const bf16* __restrict__ Qf, const bf16* __restrict__ Kf,
    bf16* __restrict__ Vf)
{
    __shared__ __align__(16) char smem[49152];
    __shared__ float rlbuf[128];
    char* Kl   = smem;
    char* Qbuf = smem + 16384;
    const int tid = threadIdx.x, lane = tid & 63, w = tid >> 6;
    const int l16 = lane * 16;
    const int g = blockIdx.x, xcd = g & 7, li = g >> 3;
    const int bh = xcd * 4 + (li >> 4);
    const int k0 = (li & 15) * 128;
    const bf16* Kbase = Kf + (size_t)bh * 131072 + (size_t)(k0 >> 6) * 4096;
    const bf16* Qbase = Qf + (size_t)bh * 131072;

    for (int j = 0; j < 4; ++j)
        gload_lds16(Kbase + (j*256 + tid)*8, Kl + (j*256 + w*64)*16);
    auto stageQ = [&](int qt, int buf) {
        const bf16* qb = Qbase + (size_t)qt * 8192;
        for (int j = 0; j < 4; ++j)
            gload_lds16(qb + (j*256 + tid)*8, Qbuf + buf*16384 + (j*256 + w*64)*16);
    };
    stageQ(0, 0);
    __syncthreads();

    bf16x8 bk[4];
    #pragma unroll
    for (int sl = 0; sl < 4; ++sl)
        bk[sl] = *(const bf16x8*)(Kl + w*4096 + sl*1024 + l16);

    float lsum = 0.f;
    int cur = 0;
    for (int qt = 0; qt < S_/128; ++qt) {
        if (qt + 1 < S_/128) stageQ(qt + 1, cur ^ 1);
        #pragma unroll
        for (int qs = 0; qs < 4; ++qs) {
            f32x16 s = {};
            __builtin_amdgcn_s_setprio(1);
            #pragma unroll
            for (int sl = 0; sl < 4; ++sl) {
                bf16x8 aq = *(const bf16x8*)(Qbuf + cur*16384 + (qs*4+sl)*1024 + l16);
                s = MFMA32(aq, bk[sl], s);
            }
            __builtin_amdgcn_s_setprio(0);
            #pragma unroll
            for (int r = 0; r < 16; ++r)
                lsum += exp2_hw(s[r]);
        }
        cur ^= 1;
        if (qt + 1 < S_/128) __syncthreads();
    }
    lsum += __shfl_xor(lsum, 32);
    if (lane < 32)
        rlbuf[w*32 + lane] = 1.0f / lsum;
    __syncthreads();

    bf16* Vb = Vf + (size_t)bh * 131072 + (size_t)(k0 >> 6) * 4096;
    for (int c = 0; c < 4; ++c) {
        const int v = c*256 + tid;
        const int kb = (v >> 9)*64 + ((v >> 6) & 3)*16 + ((v >> 5) & 1)*8;
        bf16x8* p = reinterpret_cast<bf16x8*>(Vb + v*8);
        bf16x8 x = *p, o;
        #pragma unroll
        for (int jj = 0; jj < 8; ++jj)
            o[jj] = (bf16)((float)x[jj] * rlbuf[kb + jj]);
        *p = o;
    }
}

// ---------------- pass 2: O = exp2(S') @ V'; K-step 128 (2 tiles/buffer) ----
// LDS: [0,16K) Q; [16K,48K) K dbuf (2 x 16K); [48K,80K) V dbuf (2 x 16K)
__global__ __launch_bounds__(256) void k_attn(
    const bf16* __restrict__ Qf, const bf16* __restrict__ Kf,
    const bf16* __restrict__ Vf, bf16* __restrict__ AO)
{
    __shared__ __align__(16) char smem[81920];
    char* QP   = smem;
    char* Kbuf = smem + 16384;
    char* Vbuf = smem + 49152;
    const int tid = threadIdx.x, lane = tid & 63, w = tid >> 6;
    const int l16 = lane * 16;
    const int g = blockIdx.x, xcd = g & 7, li = g >> 3;
    const int bh = xcd * 4 + (li >> 4);
    const int q0 = (li & 15) * 128;
    const bf16* Qbase = Qf + (size_t)bh * 131072 + (size_t)(q0 >> 6) * 4096;
    const bf16* Kbase = Kf + (size_t)bh * 131072;
    const bf16* Vbase = Vf + (size_t)bh * 131072;

    for (int j = 0; j < 4; ++j)
        gload_lds16(Qbase + (j*256 + tid)*8, QP + (j*256 + w*64)*16);
    // stage 128 k (two fragment-tiles, 16KB contiguous) into buffer buf
    auto stageKV = [&](int t2, int buf) {
        const bf16* kb = Kbase + (size_t)t2 * 8192;
        const bf16* vb = Vbase + (size_t)t2 * 8192;
        #pragma unroll
        for (int j = 0; j < 4; ++j) {
            gload_lds16(kb + (j*256 + tid)*8, Kbuf + buf*16384 + (j*256 + w*64)*16);
            gload_lds16(vb + (j*256 + tid)*8, Vbuf + buf*16384 + (j*256 + w*64)*16);
        }
    };
    stageKV(0, 0);
    __syncthreads();

    // hoist Q B-frags: wave's 32 q rows, 4 dh-slices (16 VGPR)
    bf16x8 bq[4];
    #pragma unroll
    for (int sl = 0; sl < 4; ++sl)
        bq[sl] = *(const bf16x8*)(QP + w*4096 + sl*1024 + l16);

    f32x16 oacc[2] = {};
    int cur = 0;
    for (int t2 = 0; t2 < 16; ++t2) {
        if (t2 + 1 < 16) stageKV(t2 + 1, cur ^ 1);

        #pragma unroll
        for (int h2 = 0; h2 < 2; ++h2) {
            char* Kc = Kbuf + cur*16384 + h2*8192;
            char* Vc = Vbuf + cur*16384 + h2*8192;

            #pragma unroll
            for (int kt = 0; kt < 2; ++kt) {
                // QK^T (swapped): D[k][q]
                f32x16 s = {};
                __builtin_amdgcn_s_setprio(1);
                #pragma unroll
                for (int sl = 0; sl < 4; ++sl) {
                    bf16x8 ak = *(const bf16x8*)(Kc + (kt*4+sl)*1024 + l16);
                    s = MFMA32(ak, bq[sl], s);
                }
                __builtin_amdgcn_s_setprio(0);

                // P = exp2 -> pack -> in-register B-frags via permlane32_swap.
                unsigned a[8];
                #pragma unroll
                for (int gg = 0; gg < 8; ++gg)
                    a[gg] = cvt_pk_bf16(exp2_hw(s[2*gg]), exp2_hw(s[2*gg+1]));

                #pragma unroll
                for (int kl = 0; kl < 2; ++kl) {
                    unsigned m0 = a[4*kl + 0], m2 = a[4*kl + 2];
                    unsigned m1 = a[4*kl + 1], m3 = a[4*kl + 3];
                    permswap32(m0, m2);
                    permswap32(m1, m3);
                    u32x4 pw = {m0, m1, m2, m3};
                    bf16x8 pf = __builtin_bit_cast(bf16x8, pw);
                    const int ksl = kt*2 + kl;
                    __builtin_amdgcn_s_setprio(1);
                    #pragma unroll
                    for (int dt = 0; dt < 2; ++dt) {
                        bf16x8 av = *(const bf16x8*)(Vc + (dt*4+ksl)*1024 + l16);
                        oacc[dt] = MFMA32(av, pf, oacc[dt]);
                    }
                    __builtin_amdgcn_s_setprio(0);
                }
            }
        }
        cur ^= 1;
        if (t2 + 1 < 16) __syncthreads();
    }

    // epilogue: O^T[d][q]: col q = lane&31, row d = dt*32 + r + 8*rg + 4*(lane>>5)
    const int b = bh >> 4, h = bh & 15;
    const int q = q0 + w*32 + (lane & 31);
    const int hi4 = (lane >> 5) * 4;
    bf16* aob = AO + ((size_t)(b*S_ + q))*E_ + h*DH_;
    #pragma unroll
    for (int dt = 0; dt < 2; ++dt)
        #pragma unroll
        for (int rg = 0; rg < 4; ++rg) {
            const int dbase = dt*32 + 8*rg + hi4;
            bf16x4 o;
            #pragma unroll
            for (int r = 0; r < 4; ++r) o[r] = (bf16)oacc[dt][rg*4 + r];
            *reinterpret_cast<bf16x4*>(aob + dbase) = o;
        }
}

extern "C" void kernel_launch(void* const* d_in, const int* in_sizes, int n_in,
                              void* d_out, int out_size, void* d_ws, size_t ws_size,
                              hipStream_t stream) {
    const float* input = (const float*)d_in[0];
    const float* Wqkv  = (const float*)d_in[1];
    const float* bqkv  = (const float*)d_in[2];
    const float* Wo    = (const float*)d_in[3];
    const float* bo    = (const float*)d_in[4];
    float* out = (float*)d_out;

    char* ws = (char*)d_ws;
    bf16*  Xb   = (bf16*) (ws + 0);
    bf16*  Wqb  = (bf16*) (ws + 8388608);
    bf16*  Wob  = (bf16*) (ws + 14680064);
    bf16*  Qfg  = (bf16*) (ws + 16777216);
    bf16*  Kfg  = (bf16*) (ws + 25165824);
    bf16*  Vfg  = (bf16*) (ws + 33554432);
    bf16*  AO   = (bf16*) (ws + 41943040);

    k_f2b3<<<(NX_ + NW_ + NWO_) / 1024, 256, 0, stream>>>(
        input, Wqkv, Wo, Xb, Wqb, Wob);

    k_gemm<0><<<768, 512, 0, stream>>>(Xb, Wqb, bqkv, Qfg, Kfg, Vfg, nullptr);

    k_colsum<<<512, 256, 0, stream>>>(Qfg, Kfg, Vfg);

    k_attn<<<512, 256, 0, stream>>>(Qfg, Kfg, Vfg, AO);

    k_gemm<1><<<256, 512, 0, stream>>>(AO, Wob, bo, nullptr, nullptr, nullptr, out);
}